// Round 10
// baseline (397.631 us; speedup 1.0000x reference)
//
#include <hip/hip_runtime.h>
#include <math.h>

#define N_NODES 50000
#define N_EDGES 800000
#define ET (N_EDGES + N_NODES)   /* 850000 edges incl. self-loops */
#define F_IN 512
#define HID 64
#define HEADS 4
#define C1 (HEADS * HID)         /* 256 */
#define NCLS 40
#define NEG_SLOPE 0.2f
#define NCHUNK ((N_NODES + 255) / 256)   /* 196 */

typedef __attribute__((ext_vector_type(8))) short short8;
typedef __attribute__((ext_vector_type(4))) float floatx4;

__device__ __forceinline__ float leaky(float x) { return fmaxf(x, NEG_SLOPE * x); }

// f32 -> bf16 round-to-nearest-even
__device__ __forceinline__ unsigned short f2bf(float f) {
    unsigned u = __float_as_uint(f);
    u += 0x7fffu + ((u >> 16) & 1u);
    return (unsigned short)(u >> 16);
}
__device__ __forceinline__ float bf2f(unsigned short u) {
    return __uint_as_float(((unsigned)u) << 16);
}

__device__ __forceinline__ void edge_sd(int e, const int* __restrict__ ei,
                                        const float* __restrict__ ew,
                                        int& s, int& d, float& w) {
    if (e < N_EDGES) { s = ei[e]; d = ei[N_EDGES + e]; w = ew[e]; }
    else             { s = d = e - N_EDGES; w = 1.f; }
}

// ======================= CSR construction (per call) =======================
__global__ void hist_kernel(const int* __restrict__ ei, int* __restrict__ cnt) {
    int e = blockIdx.x * blockDim.x + threadIdx.x;
    if (e >= ET) return;
    int d = (e < N_EDGES) ? ei[N_EDGES + e] : e - N_EDGES;
    atomicAdd(&cnt[d], 1);
}

__global__ void chunk_sum_kernel(const int* __restrict__ cnt, int* __restrict__ sums) {
    __shared__ int sm[256];
    int i = blockIdx.x * 256 + threadIdx.x;
    sm[threadIdx.x] = (i < N_NODES) ? cnt[i] : 0;
    __syncthreads();
    for (int s = 128; s > 0; s >>= 1) {
        if (threadIdx.x < s) sm[threadIdx.x] += sm[threadIdx.x + s];
        __syncthreads();
    }
    if (threadIdx.x == 0) sums[blockIdx.x] = sm[0];
}

__global__ void scan_sums_kernel(int* __restrict__ sums) {
    __shared__ int sm[256];
    int i = threadIdx.x;
    int v = (i < NCHUNK) ? sums[i] : 0;
    sm[i] = v;
    __syncthreads();
    #pragma unroll
    for (int s = 1; s < 256; s <<= 1) {
        int t = (i >= s) ? sm[i - s] : 0;
        __syncthreads();
        sm[i] += t;
        __syncthreads();
    }
    if (i < NCHUNK) sums[i] = sm[i] - v;   // exclusive
}

__global__ void rowptr_kernel(const int* __restrict__ cnt, const int* __restrict__ sums,
                              int* __restrict__ row_ptr, int* __restrict__ fill) {
    __shared__ int sm[256];
    int i = blockIdx.x * 256 + threadIdx.x;
    int v = (i < N_NODES) ? cnt[i] : 0;
    sm[threadIdx.x] = v;
    __syncthreads();
    #pragma unroll
    for (int s = 1; s < 256; s <<= 1) {
        int t = (threadIdx.x >= s) ? sm[threadIdx.x - s] : 0;
        __syncthreads();
        sm[threadIdx.x] += t;
        __syncthreads();
    }
    int excl = sm[threadIdx.x] - v + sums[blockIdx.x];
    if (i < N_NODES) { row_ptr[i] = excl; fill[i] = excl; }
}

// CSR payload: (src, edge_weight) packed in one int2 per edge
__global__ void scatter_kernel(const int* __restrict__ ei, const float* __restrict__ ew,
                               int* __restrict__ fill, int2* __restrict__ E2) {
    int e = blockIdx.x * blockDim.x + threadIdx.x;
    if (e >= ET) return;
    int s, d; float w;
    edge_sd(e, ei, ew, s, d, w);
    int pos = atomicAdd(&fill[d], 1);
    E2[pos] = make_int2(s, __float_as_int(w));
}

// ============ W1 -> bf16 transpose: WT[n][k] = bf16(W1[k][n]) ============
__global__ void wt_prep_kernel(const float* __restrict__ W, unsigned short* __restrict__ WT) {
    __shared__ float tile[32][33];
    int k0 = blockIdx.x * 32;
    int n0 = blockIdx.y * 32;
    int tx = threadIdx.x, ty = threadIdx.y;    // 32 x 8
    #pragma unroll
    for (int i = 0; i < 32; i += 8)
        tile[ty + i][tx] = W[(size_t)(k0 + ty + i) * C1 + n0 + tx];
    __syncthreads();
    #pragma unroll
    for (int i = 0; i < 32; i += 8)
        WT[(size_t)(n0 + ty + i) * F_IN + k0 + tx] = f2bf(tile[tx][ty + i]);
}

// ====== GEMM1 (bf16 MFMA) + fused alphas1: X @ W1 -> H1 (bf16), AS1/AD1 ======
__global__ __launch_bounds__(512) void gemm1_mfma_kernel(const float* __restrict__ X,
                                                         const unsigned short* __restrict__ WT,
                                                         const float* __restrict__ a_s1,
                                                         const float* __restrict__ a_d1,
                                                         unsigned short* __restrict__ H,
                                                         float* __restrict__ AS,
                                                         float* __restrict__ AD) {
    __shared__ short As[128][40];
    __shared__ short Bs[256][40];
    const int t = threadIdx.x;
    const int m0 = blockIdx.x * 128;
    const int lane = t & 63;
    const int wave = t >> 6;
    const int wm = wave >> 2;
    const int wn = wave & 3;
    const int l15 = lane & 15;
    const int quad = lane >> 4;

    const int ar = t >> 2;
    const int ac0 = (t & 3) * 8;
    const int gr = m0 + ar;
    const int bn = t >> 1;
    const int bc0 = (t & 1) * 16;

    floatx4 acc[4][4];
    #pragma unroll
    for (int i = 0; i < 4; i++)
        #pragma unroll
        for (int j = 0; j < 4; j++) acc[i][j] = (floatx4){0.f, 0.f, 0.f, 0.f};

    for (int k0 = 0; k0 < F_IN; k0 += 32) {
        float xv[8];
        if (gr < N_NODES) {
            const float4* p = (const float4*)(X + (size_t)gr * F_IN + k0 + ac0);
            float4 v0 = p[0], v1 = p[1];
            xv[0] = v0.x; xv[1] = v0.y; xv[2] = v0.z; xv[3] = v0.w;
            xv[4] = v1.x; xv[5] = v1.y; xv[6] = v1.z; xv[7] = v1.w;
        } else {
            #pragma unroll
            for (int i = 0; i < 8; i++) xv[i] = 0.f;
        }
        short8 av;
        #pragma unroll
        for (int i = 0; i < 8; i++) av[i] = (short)f2bf(xv[i]);
        *(short8*)&As[ar][ac0] = av;

        const short8* q = (const short8*)(WT + (size_t)bn * F_IN + k0 + bc0);
        *(short8*)&Bs[bn][bc0]     = q[0];
        *(short8*)&Bs[bn][bc0 + 8] = q[1];
        __syncthreads();

        short8 a[4], b[4];
        #pragma unroll
        for (int i = 0; i < 4; i++)
            a[i] = *(const short8*)&As[wm * 64 + i * 16 + l15][quad * 8];
        #pragma unroll
        for (int j = 0; j < 4; j++)
            b[j] = *(const short8*)&Bs[wn * 64 + j * 16 + l15][quad * 8];
        #pragma unroll
        for (int i = 0; i < 4; i++)
            #pragma unroll
            for (int j = 0; j < 4; j++)
                acc[i][j] = __builtin_amdgcn_mfma_f32_16x16x32_bf16(a[i], b[j], acc[i][j], 0, 0, 0);
        __syncthreads();
    }

    float asr[4], adr[4];
    #pragma unroll
    for (int j = 0; j < 4; j++) {
        asr[j] = a_s1[wn * HID + j * 16 + l15];
        adr[j] = a_d1[wn * HID + j * 16 + l15];
    }

    #pragma unroll
    for (int i = 0; i < 4; i++) {
        int rbase = m0 + wm * 64 + i * 16 + quad * 4;
        #pragma unroll
        for (int j = 0; j < 4; j++) {
            int col = wn * 64 + j * 16 + l15;
            #pragma unroll
            for (int r = 0; r < 4; r++) {
                int row = rbase + r;
                if (row < N_NODES) H[(size_t)row * C1 + col] = f2bf(acc[i][j][r]);
            }
        }
        #pragma unroll
        for (int r = 0; r < 4; r++) {
            int row = rbase + r;
            float s_ = acc[i][0][r] * asr[0] + acc[i][1][r] * asr[1]
                     + acc[i][2][r] * asr[2] + acc[i][3][r] * asr[3];
            float d_ = acc[i][0][r] * adr[0] + acc[i][1][r] * adr[1]
                     + acc[i][2][r] * adr[2] + acc[i][3][r] * adr[3];
            #pragma unroll
            for (int m = 8; m; m >>= 1) { s_ += __shfl_xor(s_, m); d_ += __shfl_xor(d_, m); }
            if (l15 == 0 && row < N_NODES) {
                AS[row * 4 + wn] = s_;
                AD[row * 4 + wn] = d_;
            }
        }
    }
}

// ---- agg1 v6: wave per node, 16-edge chunks, two-phase; phase 2 unrolled 8
//      deep (8 independent gathers in flight per lane). src via wave-uniform
//      __shfl (v_readlane, scalar pipe); pw via per-lane __shfl (needed only
//      at FMA time, overlaps gather latency). ----
__global__ __launch_bounds__(256) void agg1_csr_kernel(const int* __restrict__ row_ptr,
                                                       const int2* __restrict__ E2,
                                                       const float* __restrict__ AS,
                                                       const float* __restrict__ AD,
                                                       const unsigned short* __restrict__ H,
                                                       const float* __restrict__ b1,
                                                       unsigned short* __restrict__ OUT) {
    int n = blockIdx.x * 4 + (threadIdx.x >> 6);
    int lane = threadIdx.x & 63;
    if (n >= N_NODES) return;
    int l15 = lane & 15;
    int h = lane >> 4;
    int c0 = lane * 4;
    int beg = row_ptr[n];
    int end = (n + 1 < N_NODES) ? row_ptr[n + 1] : ET;
    float ad = AD[n * 4 + h];
    float den = 0.f;
    float a0 = 0.f, a1 = 0.f, a2 = 0.f, a3 = 0.f;

    for (int base = beg; base < end; base += 16) {
        int m = end - base; if (m > 16) m = 16;
        // phase 1: one exp per (edge, head)
        float pw = 0.f; int s = 0;
        if (l15 < m) {
            int2 e = E2[base + l15];
            s = e.x;
            float pe = __expf(leaky(AS[e.x * 4 + h] + ad));
            den += pe;
            pw = pe * __int_as_float(e.y);
        }
        // phase 2: gather + FMA, 8 loads in flight
        int p = 0;
        for (; p + 8 <= m; p += 8) {
            int s0 = __shfl(s, p);
            int s1 = __shfl(s, p + 1);
            int s2 = __shfl(s, p + 2);
            int s3 = __shfl(s, p + 3);
            int s4 = __shfl(s, p + 4);
            int s5 = __shfl(s, p + 5);
            int s6 = __shfl(s, p + 6);
            int s7 = __shfl(s, p + 7);
            uint2 u0 = *(const uint2*)(H + (size_t)s0 * C1 + c0);
            uint2 u1 = *(const uint2*)(H + (size_t)s1 * C1 + c0);
            uint2 u2 = *(const uint2*)(H + (size_t)s2 * C1 + c0);
            uint2 u3 = *(const uint2*)(H + (size_t)s3 * C1 + c0);
            uint2 u4 = *(const uint2*)(H + (size_t)s4 * C1 + c0);
            uint2 u5 = *(const uint2*)(H + (size_t)s5 * C1 + c0);
            uint2 u6 = *(const uint2*)(H + (size_t)s6 * C1 + c0);
            uint2 u7 = *(const uint2*)(H + (size_t)s7 * C1 + c0);
            float w0 = __shfl(pw, h * 16 + p);
            float w1 = __shfl(pw, h * 16 + p + 1);
            float w2 = __shfl(pw, h * 16 + p + 2);
            float w3 = __shfl(pw, h * 16 + p + 3);
            float w4 = __shfl(pw, h * 16 + p + 4);
            float w5 = __shfl(pw, h * 16 + p + 5);
            float w6 = __shfl(pw, h * 16 + p + 6);
            float w7 = __shfl(pw, h * 16 + p + 7);
            a0 += w0 * __uint_as_float(u0.x << 16)         + w1 * __uint_as_float(u1.x << 16)
                + w2 * __uint_as_float(u2.x << 16)         + w3 * __uint_as_float(u3.x << 16)
                + w4 * __uint_as_float(u4.x << 16)         + w5 * __uint_as_float(u5.x << 16)
                + w6 * __uint_as_float(u6.x << 16)         + w7 * __uint_as_float(u7.x << 16);
            a1 += w0 * __uint_as_float(u0.x & 0xffff0000u) + w1 * __uint_as_float(u1.x & 0xffff0000u)
                + w2 * __uint_as_float(u2.x & 0xffff0000u) + w3 * __uint_as_float(u3.x & 0xffff0000u)
                + w4 * __uint_as_float(u4.x & 0xffff0000u) + w5 * __uint_as_float(u5.x & 0xffff0000u)
                + w6 * __uint_as_float(u6.x & 0xffff0000u) + w7 * __uint_as_float(u7.x & 0xffff0000u);
            a2 += w0 * __uint_as_float(u0.y << 16)         + w1 * __uint_as_float(u1.y << 16)
                + w2 * __uint_as_float(u2.y << 16)         + w3 * __uint_as_float(u3.y << 16)
                + w4 * __uint_as_float(u4.y << 16)         + w5 * __uint_as_float(u5.y << 16)
                + w6 * __uint_as_float(u6.y << 16)         + w7 * __uint_as_float(u7.y << 16);
            a3 += w0 * __uint_as_float(u0.y & 0xffff0000u) + w1 * __uint_as_float(u1.y & 0xffff0000u)
                + w2 * __uint_as_float(u2.y & 0xffff0000u) + w3 * __uint_as_float(u3.y & 0xffff0000u)
                + w4 * __uint_as_float(u4.y & 0xffff0000u) + w5 * __uint_as_float(u5.y & 0xffff0000u)
                + w6 * __uint_as_float(u6.y & 0xffff0000u) + w7 * __uint_as_float(u7.y & 0xffff0000u);
        }
        for (; p + 4 <= m; p += 4) {
            int s0 = __shfl(s, p);
            int s1 = __shfl(s, p + 1);
            int s2 = __shfl(s, p + 2);
            int s3 = __shfl(s, p + 3);
            uint2 u0 = *(const uint2*)(H + (size_t)s0 * C1 + c0);
            uint2 u1 = *(const uint2*)(H + (size_t)s1 * C1 + c0);
            uint2 u2 = *(const uint2*)(H + (size_t)s2 * C1 + c0);
            uint2 u3 = *(const uint2*)(H + (size_t)s3 * C1 + c0);
            float w0 = __shfl(pw, h * 16 + p);
            float w1 = __shfl(pw, h * 16 + p + 1);
            float w2 = __shfl(pw, h * 16 + p + 2);
            float w3 = __shfl(pw, h * 16 + p + 3);
            a0 += w0 * __uint_as_float(u0.x << 16)         + w1 * __uint_as_float(u1.x << 16)
                + w2 * __uint_as_float(u2.x << 16)         + w3 * __uint_as_float(u3.x << 16);
            a1 += w0 * __uint_as_float(u0.x & 0xffff0000u) + w1 * __uint_as_float(u1.x & 0xffff0000u)
                + w2 * __uint_as_float(u2.x & 0xffff0000u) + w3 * __uint_as_float(u3.x & 0xffff0000u);
            a2 += w0 * __uint_as_float(u0.y << 16)         + w1 * __uint_as_float(u1.y << 16)
                + w2 * __uint_as_float(u2.y << 16)         + w3 * __uint_as_float(u3.y << 16);
            a3 += w0 * __uint_as_float(u0.y & 0xffff0000u) + w1 * __uint_as_float(u1.y & 0xffff0000u)
                + w2 * __uint_as_float(u2.y & 0xffff0000u) + w3 * __uint_as_float(u3.y & 0xffff0000u);
        }
        for (; p < m; p++) {
            int s0 = __shfl(s, p);
            uint2 u0 = *(const uint2*)(H + (size_t)s0 * C1 + c0);
            float w0 = __shfl(pw, h * 16 + p);
            a0 += w0 * __uint_as_float(u0.x << 16);
            a1 += w0 * __uint_as_float(u0.x & 0xffff0000u);
            a2 += w0 * __uint_as_float(u0.y << 16);
            a3 += w0 * __uint_as_float(u0.y & 0xffff0000u);
        }
    }
    den += __shfl_xor(den, 1);
    den += __shfl_xor(den, 2);
    den += __shfl_xor(den, 4);
    den += __shfl_xor(den, 8);

    float r = 1.f / (den + 1e-16f);
    float4 bv = *(const float4*)(b1 + c0);
    float v0 = a0 * r + bv.x, v1 = a1 * r + bv.y, v2 = a2 * r + bv.z, v3 = a3 * r + bv.w;
    v0 = v0 > 0.f ? v0 : 0.f;
    v1 = v1 > 0.f ? v1 : 0.f;
    v2 = v2 > 0.f ? v2 : 0.f;
    v3 = v3 > 0.f ? v3 : 0.f;
    uint2 o;
    o.x = ((unsigned)f2bf(v1) << 16) | (unsigned)f2bf(v0);
    o.y = ((unsigned)f2bf(v3) << 16) | (unsigned)f2bf(v2);
    *(uint2*)(OUT + (size_t)n * C1 + c0) = o;
}

// ====== GEMM2 (bf16 MFMA) + fused alphas2: OUT1b @ W2 -> H2b (bf16), AS2/AD2 ======
#define BROW 264   /* LDS row stride for Bs2: 528B, 16B-aligned */
__global__ __launch_bounds__(512) void gemm2_mfma_kernel(const unsigned short* __restrict__ A,
                                                         const float* __restrict__ W2,
                                                         const float* __restrict__ a_s2,
                                                         const float* __restrict__ a_d2,
                                                         unsigned short* __restrict__ H2b,
                                                         float* __restrict__ AS2,
                                                         float* __restrict__ AD2) {
    __shared__ short As[256][40];        // 20 KB
    __shared__ short Bs[48 * BROW];      // 25.3 KB
    const int t = threadIdx.x;
    const int m0 = blockIdx.x * 256;
    const int lane = t & 63;
    const int wave = t >> 6;
    const int l15 = lane & 15;
    const int quad = lane >> 4;

    for (int i = t; i < 48 * 256; i += 512) {
        int n = i >> 8, k = i & 255;
        float v = (n < NCLS) ? W2[k * NCLS + n] : 0.f;
        Bs[n * BROW + k] = (short)f2bf(v);
    }

    const int ar = t >> 1;
    const int ac0 = (t & 1) * 16;

    floatx4 acc[2][3];
    #pragma unroll
    for (int i = 0; i < 2; i++)
        #pragma unroll
        for (int j = 0; j < 3; j++) acc[i][j] = (floatx4){0.f, 0.f, 0.f, 0.f};

    for (int k0 = 0; k0 < C1; k0 += 32) {
        const short8* q = (const short8*)(A + (size_t)(m0 + ar) * C1 + k0 + ac0);
        short8 v0 = q[0], v1 = q[1];
        __syncthreads();
        *(short8*)&As[ar][ac0]     = v0;
        *(short8*)&As[ar][ac0 + 8] = v1;
        __syncthreads();

        short8 a[2], b[3];
        #pragma unroll
        for (int i = 0; i < 2; i++)
            a[i] = *(const short8*)&As[wave * 32 + i * 16 + l15][quad * 8];
        #pragma unroll
        for (int j = 0; j < 3; j++)
            b[j] = *(const short8*)&Bs[(j * 16 + l15) * BROW + k0 + quad * 8];
        #pragma unroll
        for (int i = 0; i < 2; i++)
            #pragma unroll
            for (int j = 0; j < 3; j++)
                acc[i][j] = __builtin_amdgcn_mfma_f32_16x16x32_bf16(a[i], b[j], acc[i][j], 0, 0, 0);
    }

    float asr[3], adr[3];
    #pragma unroll
    for (int j = 0; j < 3; j++) {
        int col = j * 16 + l15;
        asr[j] = (col < NCLS) ? a_s2[col] : 0.f;
        adr[j] = (col < NCLS) ? a_d2[col] : 0.f;
    }

    #pragma unroll
    for (int i = 0; i < 2; i++) {
        #pragma unroll
        for (int r = 0; r < 4; r++) {
            int row = m0 + wave * 32 + i * 16 + quad * 4 + r;
            float s_ = acc[i][0][r] * asr[0] + acc[i][1][r] * asr[1] + acc[i][2][r] * asr[2];
            float d_ = acc[i][0][r] * adr[0] + acc[i][1][r] * adr[1] + acc[i][2][r] * adr[2];
            #pragma unroll
            for (int m = 8; m; m >>= 1) { s_ += __shfl_xor(s_, m); d_ += __shfl_xor(d_, m); }
            if (l15 == 0 && row < N_NODES) { AS2[row] = s_; AD2[row] = d_; }
            #pragma unroll
            for (int j = 0; j < 3; j++) {
                int col = j * 16 + l15;
                if (col < NCLS && row < N_NODES)
                    H2b[(size_t)row * NCLS + col] = f2bf(acc[i][j][r]);
            }
        }
    }
}

// ---- agg2 v6: wave per node, 64-edge chunks, two-phase, 8-deep unroll ----
__global__ __launch_bounds__(256) void agg2_csr_kernel(const int* __restrict__ row_ptr,
                                                       const int2* __restrict__ E2,
                                                       const float* __restrict__ AS,
                                                       const float* __restrict__ AD,
                                                       const unsigned short* __restrict__ H2b,
                                                       const float* __restrict__ b2,
                                                       float* __restrict__ OUT) {
    int lane = threadIdx.x & 63;
    int n = blockIdx.x * 4 + (threadIdx.x >> 6);
    if (n >= N_NODES) return;
    int beg = row_ptr[n];
    int end = (n + 1 < N_NODES) ? row_ptr[n + 1] : ET;
    float ad = AD[n];
    bool act = lane < NCLS;
    float den = 0.f, acc = 0.f;

    for (int base = beg; base < end; base += 64) {
        int m = end - base; if (m > 64) m = 64;
        float pw = 0.f; int s = 0;
        if (lane < m) {
            int2 e = E2[base + lane];
            s = e.x;
            float pe = __expf(leaky(AS[e.x] + ad));
            den += pe;
            pw = pe * __int_as_float(e.y);
        }
        int p = 0;
        for (; p + 8 <= m; p += 8) {
            int s0 = __shfl(s, p);
            int s1 = __shfl(s, p + 1);
            int s2 = __shfl(s, p + 2);
            int s3 = __shfl(s, p + 3);
            int s4 = __shfl(s, p + 4);
            int s5 = __shfl(s, p + 5);
            int s6 = __shfl(s, p + 6);
            int s7 = __shfl(s, p + 7);
            float w0 = __shfl(pw, p);
            float w1 = __shfl(pw, p + 1);
            float w2 = __shfl(pw, p + 2);
            float w3 = __shfl(pw, p + 3);
            float w4 = __shfl(pw, p + 4);
            float w5 = __shfl(pw, p + 5);
            float w6 = __shfl(pw, p + 6);
            float w7 = __shfl(pw, p + 7);
            if (act) {
                float h0 = bf2f(H2b[(size_t)s0 * NCLS + lane]);
                float h1 = bf2f(H2b[(size_t)s1 * NCLS + lane]);
                float h2 = bf2f(H2b[(size_t)s2 * NCLS + lane]);
                float h3 = bf2f(H2b[(size_t)s3 * NCLS + lane]);
                float h4 = bf2f(H2b[(size_t)s4 * NCLS + lane]);
                float h5 = bf2f(H2b[(size_t)s5 * NCLS + lane]);
                float h6 = bf2f(H2b[(size_t)s6 * NCLS + lane]);
                float h7 = bf2f(H2b[(size_t)s7 * NCLS + lane]);
                acc += w0 * h0 + w1 * h1 + w2 * h2 + w3 * h3
                     + w4 * h4 + w5 * h5 + w6 * h6 + w7 * h7;
            }
        }
        for (; p + 4 <= m; p += 4) {
            int s0 = __shfl(s, p);
            int s1 = __shfl(s, p + 1);
            int s2 = __shfl(s, p + 2);
            int s3 = __shfl(s, p + 3);
            float w0 = __shfl(pw, p);
            float w1 = __shfl(pw, p + 1);
            float w2 = __shfl(pw, p + 2);
            float w3 = __shfl(pw, p + 3);
            if (act) {
                float h0 = bf2f(H2b[(size_t)s0 * NCLS + lane]);
                float h1 = bf2f(H2b[(size_t)s1 * NCLS + lane]);
                float h2 = bf2f(H2b[(size_t)s2 * NCLS + lane]);
                float h3 = bf2f(H2b[(size_t)s3 * NCLS + lane]);
                acc += w0 * h0 + w1 * h1 + w2 * h2 + w3 * h3;
            }
        }
        for (; p < m; p++) {
            int s0 = __shfl(s, p);
            float w0 = __shfl(pw, p);
            if (act) acc += w0 * bf2f(H2b[(size_t)s0 * NCLS + lane]);
        }
    }
    den += __shfl_xor(den, 1);
    den += __shfl_xor(den, 2);
    den += __shfl_xor(den, 4);
    den += __shfl_xor(den, 8);
    den += __shfl_xor(den, 16);
    den += __shfl_xor(den, 32);
    if (act) {
        float r = 1.f / (den + 1e-16f);
        OUT[(size_t)n * NCLS + lane] = acc * r + b2[lane];
    }
}

extern "C" void kernel_launch(void* const* d_in, const int* in_sizes, int n_in,
                              void* d_out, int out_size, void* d_ws, size_t ws_size,
                              hipStream_t stream) {
    const float* x    = (const float*)d_in[0];
    const int*   ei   = (const int*)d_in[1];
    const float* ew   = (const float*)d_in[2];
    const float* W1   = (const float*)d_in[3];
    const float* a_s1 = (const float*)d_in[4];
    const float* a_d1 = (const float*)d_in[5];
    const float* b1   = (const float*)d_in[6];
    const float* W2   = (const float*)d_in[7];
    const float* a_s2 = (const float*)d_in[8];
    const float* a_d2 = (const float*)d_in[9];
    const float* b2   = (const float*)d_in[10];
    float* out = (float*)d_out;

    unsigned short* H1b  = (unsigned short*)d_ws;
    unsigned short* OUT1b = H1b + (size_t)N_NODES * C1;
    float* AS1  = (float*)(OUT1b + (size_t)N_NODES * C1);
    float* AD1  = AS1 + N_NODES * HEADS;
    int* row_ptr = (int*)(AD1 + N_NODES * HEADS);
    int* cnt  = row_ptr + N_NODES;
    int* fill = cnt + N_NODES;
    int2* E2  = (int2*)(fill + N_NODES);
    int* sums = (int*)(E2 + ET);
    unsigned short* WT = (unsigned short*)(sums + NCHUNK);
    unsigned short* H2b = H1b;             // alias (H1b dead before gemm2 writes)
    float* AS2  = (float*)(H2b + (size_t)N_NODES * NCLS);
    float* AD2  = AS2 + N_NODES;

    // ---- CSR build + weight prep ----
    hipMemsetAsync(cnt, 0, N_NODES * sizeof(int), stream);
    wt_prep_kernel<<<dim3(F_IN / 32, C1 / 32), dim3(32, 8), 0, stream>>>(W1, WT);
    hist_kernel<<<(ET + 255) / 256, 256, 0, stream>>>(ei, cnt);
    chunk_sum_kernel<<<NCHUNK, 256, 0, stream>>>(cnt, sums);
    scan_sums_kernel<<<1, 256, 0, stream>>>(sums);
    rowptr_kernel<<<NCHUNK, 256, 0, stream>>>(cnt, sums, row_ptr, fill);
    scatter_kernel<<<(ET + 255) / 256, 256, 0, stream>>>(ei, ew, fill, E2);

    // ---- layer 1 ----
    gemm1_mfma_kernel<<<(N_NODES + 127) / 128, 512, 0, stream>>>(x, WT, a_s1, a_d1, H1b, AS1, AD1);
    agg1_csr_kernel<<<(N_NODES + 3) / 4, 256, 0, stream>>>(row_ptr, E2, AS1, AD1, H1b, b1, OUT1b);

    // ---- layer 2 ----
    gemm2_mfma_kernel<<<(N_NODES + 255) / 256, 512, 0, stream>>>(OUT1b, W2, a_s2, a_d2, H2b, AS2, AD2);
    agg2_csr_kernel<<<(N_NODES + 3) / 4, 256, 0, stream>>>(row_ptr, E2, AS2, AD2, H2b, b2, out);
}